// Round 5
// baseline (79.927 us; speedup 1.0000x reference)
//
#include <hip/hip_runtime.h>
#include <hip/hip_cooperative_groups.h>
#include <cmath>

namespace cg = cooperative_groups;

#define NP 64    // patients
#define NM 16    // mats per patient
#define NA 512   // input_size (row length)
#define NB 128   // rows per mat
#define H1 256
#define H2 256
#define NC 32

__device__ __forceinline__ float sigmoid_(float x) {
    return 1.0f / (1.0f + __expf(-x));
}

__device__ __forceinline__ float dot4(float4 a, float4 b, float acc) {
    acc = fmaf(a.x, b.x, acc);
    acc = fmaf(a.y, b.y, acc);
    acc = fmaf(a.z, b.z, acc);
    acc = fmaf(a.w, b.w, acc);
    return acc;
}

// Single cooperative dispatch, 64 blocks x 256 threads, 3 phases with grid.sync().
// Phase A: fc1 with (patient-tile x output-tile) blocks -> per-block W1 slice 64 KB.
// Phase B: LSTM gates i,g,o (f dead: c0=0), 4 j's/block, weight reads wave-uniform.
// Phase C: fc3 + softmax, one block per patient.
// Only x[p, NM-1, :, NB-1] reaches the output; W_hh term dead (h0=0).
extern "C" __global__ __launch_bounds__(256)
void rnn_coop(const float* __restrict__ x,
              const float* __restrict__ W1, const float* __restrict__ b1,
              const float* __restrict__ W_ih,
              const float* __restrict__ b_ih, const float* __restrict__ b_hh,
              const float* __restrict__ W3, const float* __restrict__ b3,
              float* __restrict__ h1ws, float* __restrict__ hws,
              float* __restrict__ out)
{
    cg::grid_group grid = cg::this_grid();
    const int t = threadIdx.x;
    const int b = blockIdx.x;

    __shared__ float rows[8][NA];   // 16 KB (phase A)
    __shared__ float logits[NC];    // (phase C)

    // ---------------- Phase A: gather + fc1 ----------------
    {
        const int pt = b >> 3;          // patient tile 0..7
        const int ot = b & 7;           // output tile 0..7
        for (int idx = t; idx < 8 * NA; idx += 256) {
            const int pl = idx >> 9;
            const int a  = idx & (NA - 1);
            const size_t gi = ((((size_t)(pt * 8 + pl) * NM + (NM - 1)) * NA + a) * NB) + (NB - 1);
            rows[pl][a] = x[gi];
        }
        __syncthreads();

        const int pl = t >> 5;          // 0..7
        const int ol = t & 31;          // 0..31
        const int o  = ot * 32 + ol;

        const float4* w = (const float4*)(W1 + (size_t)o * NA);
        const float4* r = (const float4*)rows[pl];
        float a0 = 0.f, a1 = 0.f, a2 = 0.f, a3 = 0.f;
        #pragma unroll 8
        for (int k = 0; k < NA / 4; k += 4) {
            a0 = dot4(w[k + 0], r[k + 0], a0);
            a1 = dot4(w[k + 1], r[k + 1], a1);
            a2 = dot4(w[k + 2], r[k + 2], a2);
            a3 = dot4(w[k + 3], r[k + 3], a3);
        }
        h1ws[(size_t)(pt * 8 + pl) * H1 + o] =
            fmaxf((a0 + a1) + (a2 + a3) + b1[o], 0.f);
    }
    grid.sync();

    // ---------------- Phase B: LSTM gates -> h ----------------
    {
        const int j = b * 4 + (t >> 6);   // gate row 0..255
        const int p = t & 63;             // patient

        const float4* wi = (const float4*)(W_ih + (size_t)j * H1);
        const float4* wg = (const float4*)(W_ih + (size_t)(2 * H2 + j) * H1);
        const float4* wo = (const float4*)(W_ih + (size_t)(3 * H2 + j) * H1);
        const float4* hv = (const float4*)(h1ws + (size_t)p * H1);

        float i0 = 0.f, i1 = 0.f, g0 = 0.f, g1 = 0.f, o0 = 0.f, o1 = 0.f;
        #pragma unroll 8
        for (int k = 0; k < H1 / 4; k += 2) {
            float4 h4a = hv[k], h4b = hv[k + 1];
            i0 = dot4(wi[k], h4a, i0);  i1 = dot4(wi[k + 1], h4b, i1);
            g0 = dot4(wg[k], h4a, g0);  g1 = dot4(wg[k + 1], h4b, g1);
            o0 = dot4(wo[k], h4a, o0);  o1 = dot4(wo[k + 1], h4b, o1);
        }
        const float ai = i0 + i1 + b_ih[j]            + b_hh[j];
        const float ag = g0 + g1 + b_ih[2 * H2 + j]   + b_hh[2 * H2 + j];
        const float ao = o0 + o1 + b_ih[3 * H2 + j]   + b_hh[3 * H2 + j];
        const float c = sigmoid_(ai) * tanhf(ag);
        const float h = sigmoid_(ao) * tanhf(c);
        hws[(size_t)p * H2 + j] = fmaxf(h, 0.f);
    }
    grid.sync();

    // ---------------- Phase C: fc3 + softmax (block = patient) ----------------
    {
        const int p = b;
        const int g = t >> 3;   // class 0..31
        const int l = t & 7;

        const float4* w  = (const float4*)(W3 + (size_t)g * H2);
        const float4* hv = (const float4*)(hws + (size_t)p * H2);
        float acc = 0.f;
        #pragma unroll
        for (int j = 0; j < 8; ++j)
            acc = dot4(w[l + 8 * j], hv[l + 8 * j], acc);
        acc += __shfl_down(acc, 4, 64);
        acc += __shfl_down(acc, 2, 64);
        acc += __shfl_down(acc, 1, 64);
        if (l == 0) logits[g] = acc + b3[g];
        __syncthreads();

        if (t < NC) {
            float v = logits[t];
            float m = v;
            #pragma unroll
            for (int off = 16; off; off >>= 1) m = fmaxf(m, __shfl_xor(m, off, 64));
            float e = __expf(v - m);
            float s = e;
            #pragma unroll
            for (int off = 16; off; off >>= 1) s += __shfl_xor(s, off, 64);
            out[p * NC + t] = e / s;
        }
    }
}

extern "C" void kernel_launch(void* const* d_in, const int* in_sizes, int n_in,
                              void* d_out, int out_size, void* d_ws, size_t ws_size,
                              hipStream_t stream) {
    const float* x    = (const float*)d_in[0];
    const float* W1   = (const float*)d_in[1];
    const float* b1   = (const float*)d_in[2];
    const float* W_ih = (const float*)d_in[3];
    // d_in[4] = W_hh: unused (h0 = 0 kills the recurrent term)
    const float* b_ih = (const float*)d_in[5];
    const float* b_hh = (const float*)d_in[6];
    const float* W3   = (const float*)d_in[7];
    const float* b3   = (const float*)d_in[8];
    float* out = (float*)d_out;

    float* h1 = (float*)d_ws;                 // 64*256 f32 = 64 KB
    float* h  = h1 + (size_t)NP * H1;         // next 64 KB

    void* args[] = {
        (void*)&x, (void*)&W1, (void*)&b1, (void*)&W_ih,
        (void*)&b_ih, (void*)&b_hh, (void*)&W3, (void*)&b3,
        (void*)&h1, (void*)&h, (void*)&out
    };
    hipLaunchCooperativeKernel((const void*)rnn_coop, dim3(NP), dim3(256),
                               args, 0, stream);
}

// Round 6
// 43.269 us; speedup vs baseline: 1.8472x; 1.8472x over previous
//
#include <hip/hip_runtime.h>
#include <cmath>

#define NP 64    // patients
#define NM 16    // mats per patient
#define NA 512   // input_size (row length)
#define NB 128   // rows per mat
#define H1 256
#define H2 256
#define NC 32

__device__ __forceinline__ float sigmoid_(float x) {
    return 1.0f / (1.0f + __expf(-x));
}

__device__ __forceinline__ float dot4(float4 a, float4 b, float acc) {
    acc = fmaf(a.x, b.x, acc);
    acc = fmaf(a.y, b.y, acc);
    acc = fmaf(a.z, b.z, acc);
    acc = fmaf(a.w, b.w, acc);
    return acc;
}

// One block per patient, 1024 threads (16 waves -> 4 waves/SIMD for latency hiding).
// Only x[p, NM-1, :, NB-1] reaches the output (reference keeps outs[:, -1, :]);
// h0=c0=0 kills the W_hh term and the forget gate.
// fc1 / LSTM dots are split 4-ways per output (4-lane shuffle reduce).
extern "C" __global__ __launch_bounds__(1024)
void rnn_fused(const float* __restrict__ x,
               const float* __restrict__ W1, const float* __restrict__ b1,
               const float* __restrict__ W_ih,
               const float* __restrict__ b_ih, const float* __restrict__ b_hh,
               const float* __restrict__ W3, const float* __restrict__ b3,
               float* __restrict__ out)
{
    __shared__ float row[NA];    // 2 KB
    __shared__ float h1s[H1];    // 1 KB
    __shared__ float hs[H2];     // 1 KB
    __shared__ float logits[NC];

    const int p = blockIdx.x;
    const int t = threadIdx.x;

    // ---- gather: x[p, NM-1, a, NB-1], element stride NB ----
    const size_t abase = ((size_t)p * NM + (NM - 1)) * NA;
    if (t < NA)
        row[t] = x[(abase + t) * NB + (NB - 1)];
    __syncthreads();

    // ---- fc1 + ReLU: o = t>>2 (0..255), quarter q = t&3 (128 MACs each) ----
    {
        const int o = t >> 2;
        const int q = t & 3;
        const float4* w = (const float4*)(W1 + (size_t)o * NA) + q * 32;
        const float4* r = (const float4*)row + q * 32;
        float a0 = 0.f, a1 = 0.f;
        #pragma unroll 8
        for (int k = 0; k < 32; k += 2) {
            a0 = dot4(w[k],     r[k],     a0);
            a1 = dot4(w[k + 1], r[k + 1], a1);
        }
        float acc = a0 + a1;
        acc += __shfl_down(acc, 2, 4);
        acc += __shfl_down(acc, 1, 4);
        if (q == 0) h1s[o] = fmaxf(acc + b1[o], 0.f);
    }
    __syncthreads();

    // ---- LSTM step (h0=c0=0): gates i,g,o; j = t>>2, quarter q = t&3 ----
    {
        const int j = t >> 2;
        const int q = t & 3;
        const float4* wi = (const float4*)(W_ih + (size_t)j * H1) + q * 16;
        const float4* wg = (const float4*)(W_ih + (size_t)(2 * H2 + j) * H1) + q * 16;
        const float4* wo = (const float4*)(W_ih + (size_t)(3 * H2 + j) * H1) + q * 16;
        const float4* hv = (const float4*)h1s + q * 16;
        float ai = 0.f, ag = 0.f, ao = 0.f;
        #pragma unroll 4
        for (int k = 0; k < 16; ++k) {
            float4 h4 = hv[k];
            ai = dot4(wi[k], h4, ai);
            ag = dot4(wg[k], h4, ag);
            ao = dot4(wo[k], h4, ao);
        }
        ai += __shfl_down(ai, 2, 4);  ai += __shfl_down(ai, 1, 4);
        ag += __shfl_down(ag, 2, 4);  ag += __shfl_down(ag, 1, 4);
        ao += __shfl_down(ao, 2, 4);  ao += __shfl_down(ao, 1, 4);
        if (q == 0) {
            ai += b_ih[j]            + b_hh[j];
            ag += b_ih[2 * H2 + j]   + b_hh[2 * H2 + j];
            ao += b_ih[3 * H2 + j]   + b_hh[3 * H2 + j];
            const float c = sigmoid_(ai) * tanhf(ag);
            const float h = sigmoid_(ao) * tanhf(c);
            hs[j] = fmaxf(h, 0.f);
        }
    }
    __syncthreads();

    // ---- fc3: class g = t>>5 (0..31), lane l = t&31 (8 MACs each) ----
    {
        const int g = t >> 5;
        const int l = t & 31;
        const float4* w  = (const float4*)(W3 + (size_t)g * H2) + l * 2;
        const float4* hv = (const float4*)hs + l * 2;
        float acc = dot4(w[0], hv[0], 0.f);
        acc = dot4(w[1], hv[1], acc);
        acc += __shfl_down(acc, 16, 32);
        acc += __shfl_down(acc, 8, 32);
        acc += __shfl_down(acc, 4, 32);
        acc += __shfl_down(acc, 2, 32);
        acc += __shfl_down(acc, 1, 32);
        if (l == 0) logits[g] = acc + b3[g];
    }
    __syncthreads();

    // ---- softmax over 32 classes (lanes 0..31 of wave 0) ----
    if (t < NC) {
        float v = logits[t];
        float m = v;
        #pragma unroll
        for (int off = 16; off; off >>= 1) m = fmaxf(m, __shfl_xor(m, off, 64));
        float e = __expf(v - m);
        float s = e;
        #pragma unroll
        for (int off = 16; off; off >>= 1) s += __shfl_xor(s, off, 64);
        out[p * NC + t] = e / s;
    }
}

extern "C" void kernel_launch(void* const* d_in, const int* in_sizes, int n_in,
                              void* d_out, int out_size, void* d_ws, size_t ws_size,
                              hipStream_t stream) {
    const float* x    = (const float*)d_in[0];
    const float* W1   = (const float*)d_in[1];
    const float* b1   = (const float*)d_in[2];
    const float* W_ih = (const float*)d_in[3];
    // d_in[4] = W_hh: unused (h0 = 0 kills the recurrent term)
    const float* b_ih = (const float*)d_in[5];
    const float* b_hh = (const float*)d_in[6];
    const float* W3   = (const float*)d_in[7];
    const float* b3   = (const float*)d_in[8];
    float* out = (float*)d_out;

    hipLaunchKernelGGL(rnn_fused, dim3(NP), dim3(1024), 0, stream,
                       x, W1, b1, W_ih, b_ih, b_hh, W3, b3, out);
}